// Round 3
// baseline (722.888 us; speedup 1.0000x reference)
//
#include <hip/hip_runtime.h>

#define BB 32
#define SS 4096
#define DD 1024
#define OO 1024
#define RAD 64
#define NSPLIT 4
#define NBLK (SS / 16)   // k_score blocks per batch = 256
#define OTILE 16
#define KTILE 256
#define NKT ((DD + DD) / KTILE)  // 8 k-tiles over K=2048

typedef float f4 __attribute__((ext_vector_type(4)));
typedef float f2 __attribute__((ext_vector_type(2)));

__device__ __forceinline__ float dot4(f4 a, f4 q) {
  return a.x * q.x + a.y * q.y + a.z * q.z + a.w * q.w;
}

// ---- Kernel 1: score[b,s] = dot(src[b,s,:], tgt[b,:]) + fused block softmax partials ----
// grid (S/16, B), 256 threads = 4 waves, 4 s per wave. All 16 row-loads issued
// before arithmetic (MLP); interleaved butterflies; per-block (max, sumexp)
// partials written so no separate full-score stats pass is needed.
__global__ __launch_bounds__(256) void k_score(const float* __restrict__ src,
                                               const float* __restrict__ tgt,
                                               float* __restrict__ score,
                                               float* __restrict__ blkstats) {
  const int b = blockIdx.y;
  const int wave = threadIdx.x >> 6;
  const int lane = threadIdx.x & 63;
  const int s_base = blockIdx.x * 16 + wave * 4;

  const f4* tv = (const f4*)(tgt + (size_t)b * DD);
  f4 q0 = tv[lane], q1 = tv[64 + lane], q2 = tv[128 + lane], q3 = tv[192 + lane];

  const f4* r0 = (const f4*)(src + ((size_t)b * SS + s_base) * DD) + lane;
  const f4* r1 = r0 + 256;
  const f4* r2 = r0 + 512;
  const f4* r3 = r0 + 768;

  f4 a00 = __builtin_nontemporal_load(r0);
  f4 a01 = __builtin_nontemporal_load(r0 + 64);
  f4 a02 = __builtin_nontemporal_load(r0 + 128);
  f4 a03 = __builtin_nontemporal_load(r0 + 192);
  f4 a10 = __builtin_nontemporal_load(r1);
  f4 a11 = __builtin_nontemporal_load(r1 + 64);
  f4 a12 = __builtin_nontemporal_load(r1 + 128);
  f4 a13 = __builtin_nontemporal_load(r1 + 192);
  f4 a20 = __builtin_nontemporal_load(r2);
  f4 a21 = __builtin_nontemporal_load(r2 + 64);
  f4 a22 = __builtin_nontemporal_load(r2 + 128);
  f4 a23 = __builtin_nontemporal_load(r2 + 192);
  f4 a30 = __builtin_nontemporal_load(r3);
  f4 a31 = __builtin_nontemporal_load(r3 + 64);
  f4 a32 = __builtin_nontemporal_load(r3 + 128);
  f4 a33 = __builtin_nontemporal_load(r3 + 192);

  float p0 = (dot4(a00, q0) + dot4(a01, q1)) + (dot4(a02, q2) + dot4(a03, q3));
  float p1 = (dot4(a10, q0) + dot4(a11, q1)) + (dot4(a12, q2) + dot4(a13, q3));
  float p2 = (dot4(a20, q0) + dot4(a21, q1)) + (dot4(a22, q2) + dot4(a23, q3));
  float p3 = (dot4(a30, q0) + dot4(a31, q1)) + (dot4(a32, q2) + dot4(a33, q3));

  for (int off = 32; off > 0; off >>= 1) {
    p0 += __shfl_xor(p0, off);
    p1 += __shfl_xor(p1, off);
    p2 += __shfl_xor(p2, off);
    p3 += __shfl_xor(p3, off);
  }

  float sel = (lane == 0) ? p0 : ((lane == 1) ? p1 : ((lane == 2) ? p2 : p3));
  if (lane < 4) score[(size_t)b * SS + s_base + lane] = sel;

  __shared__ float rowv[16];
  if (lane < 4) rowv[wave * 4 + lane] = sel;
  __syncthreads();
  if (threadIdx.x == 0) {
    float m = rowv[0];
    #pragma unroll
    for (int i = 1; i < 16; ++i) m = fmaxf(m, rowv[i]);
    float l = 0.f;
    #pragma unroll
    for (int i = 0; i < 16; ++i) l += expf(rowv[i] - m);
    float* bs = blkstats + ((size_t)b * NBLK + blockIdx.x) * 2;
    bs[0] = m; bs[1] = l;
  }
}

// ---- Kernel 2: fused (combine blkstats -> m,l) + windowed weighted sum ----
// grid (NSPLIT, B). Every block re-derives the batch softmax stats from the
// 256 blkstats pairs (2 KB, L2-hot, wave-parallel online merge) -- removes the
// separate k_combine dispatch and the stats round-trip.
__global__ __launch_bounds__(256) void k_weighted(const float* __restrict__ src,
                                                  const float* __restrict__ score,
                                                  const float* __restrict__ blkstats,
                                                  const int* __restrict__ pos,
                                                  float* __restrict__ partial) {
  const int b = blockIdx.y;
  const int split = blockIdx.x;
  const int wave = threadIdx.x >> 6;
  const int lane = threadIdx.x & 63;

  // combine: thread t owns blkstats pair t (NBLK == 256 == blockDim.x)
  const float* bs = blkstats + (size_t)b * NBLK * 2;
  float m = bs[2 * threadIdx.x];
  float l = bs[2 * threadIdx.x + 1];
  for (int off = 32; off > 0; off >>= 1) {
    float m2 = __shfl_xor(m, off);
    float l2 = __shfl_xor(l, off);
    float mm = fmaxf(m, m2);
    l = l * expf(m - mm) + l2 * expf(m2 - mm);
    m = mm;
  }
  __shared__ float sm[4], sl[4];
  if (lane == 0) { sm[wave] = m; sl[wave] = l; }
  __syncthreads();
  const float M = fmaxf(fmaxf(sm[0], sm[1]), fmaxf(sm[2], sm[3]));
  const float L = sl[0] * expf(sm[0] - M) + sl[1] * expf(sm[1] - M) +
                  sl[2] * expf(sm[2] - M) + sl[3] * expf(sm[3] - M);
  const float inv = 1.f / L;

  // windowed weighted sum: pos_w < 1e-14 beyond |rel|=64
  const int p = pos[b];
  int w0 = p - RAD; if (w0 < 0) w0 = 0;
  int w1 = p + RAD + 1; if (w1 > SS) w1 = SS;
  const int len = w1 - w0;
  const int chunk = (len + NSPLIT - 1) / NSPLIT;
  int cs = w0 + split * chunk;
  int ce = cs + chunk; if (ce > w1) ce = w1;

  const int t = threadIdx.x;
  float a0 = 0.f, a1 = 0.f, a2 = 0.f, a3 = 0.f;
  for (int s = cs; s < ce; ++s) {
    float rel = (float)(s - p);
    float w = expf(score[(size_t)b * SS + s] - M) * inv * expf(rel * rel * (-1.f / 128.f));
    f4 v = ((const f4*)(src + ((size_t)b * SS + s) * DD))[t];
    a0 += w * v.x; a1 += w * v.y; a2 += w * v.z; a3 += w * v.w;
  }
  f4* outp = (f4*)(partial + ((size_t)split * BB + b) * DD);
  f4 o; o.x = a0; o.y = a1; o.z = a2; o.w = a3;
  outp[t] = o;  // always write: ws is re-poisoned
}

// ---- Kernel 3: batched out = tanh([tgt | weighted] @ W) ----
// M=32 GEMM: grid = OO/OTILE = 64 blocks, each owns a 16-col W stripe read
// EXACTLY ONCE (total W traffic 8 MB line-granular vs 256 MB in the per-batch
// version). LDS: ct[32][257] (padded: bank (b*257+k)%32 distinct across the
// 32 lanes) + wt[256][8] f2 (broadcast reads, conflict-free).
__global__ __launch_bounds__(256) void k_out(const float* __restrict__ tgt,
                                             const float* __restrict__ partial,
                                             const float* __restrict__ W,
                                             float* __restrict__ out) {
  const int o0 = blockIdx.x * OTILE;
  __shared__ float ct[32][KTILE + 1];
  __shared__ f2 wt[KTILE][OTILE / 2];
  const int tid = threadIdx.x;
  const int bown = tid & 31;   // batch this thread accumulates for
  const int opair = tid >> 5;  // which pair of output columns (0..7)
  float acc0 = 0.f, acc1 = 0.f;

  for (int kt = 0; kt < NKT; ++kt) {
    const int k0 = kt * KTILE;
    __syncthreads();  // protect previous tile before overwrite
    if (k0 < DD) {
      for (int idx = tid; idx < 32 * KTILE; idx += 256) {
        const int bb = idx >> 8;           // KTILE == 256
        const int kk = idx & (KTILE - 1);
        ct[bb][kk] = tgt[(size_t)bb * DD + k0 + kk];
      }
    } else {
      const int kd0 = k0 - DD;
      for (int idx = tid; idx < 32 * KTILE; idx += 256) {
        const int bb = idx >> 8;
        const int kk = idx & (KTILE - 1);
        const size_t base = (size_t)bb * DD + kd0 + kk;
        float v = partial[base] +
                  partial[(size_t)1 * BB * DD + base] +
                  partial[(size_t)2 * BB * DD + base] +
                  partial[(size_t)3 * BB * DD + base];
        ct[bb][kk] = v;
      }
    }
    for (int idx = tid; idx < KTILE * (OTILE / 2); idx += 256) {
      const int row = idx >> 3;            // OTILE/2 == 8
      const int c2 = idx & 7;
      wt[row][c2] = *(const f2*)(W + (size_t)(k0 + row) * OO + o0 + c2 * 2);
    }
    __syncthreads();
    #pragma unroll 8
    for (int kk = 0; kk < KTILE; ++kk) {
      float c = ct[bown][kk];
      f2 w = wt[kk][opair];
      acc0 += c * w.x;
      acc1 += c * w.y;
    }
  }
  const int o = o0 + opair * 2;
  out[(size_t)bown * OO + o]     = tanhf(acc0);
  out[(size_t)bown * OO + o + 1] = tanhf(acc1);
}

extern "C" void kernel_launch(void* const* d_in, const int* in_sizes, int n_in,
                              void* d_out, int out_size, void* d_ws, size_t ws_size,
                              hipStream_t stream) {
  const float* src = (const float*)d_in[0];
  const float* tgt = (const float*)d_in[1];
  const int* pos   = (const int*)d_in[2];
  const float* W   = (const float*)d_in[3];
  float* out = (float*)d_out;

  float* ws       = (float*)d_ws;
  float* score    = ws;                                   // B*S          = 131072 floats
  float* blkstats = score + (size_t)BB * SS;              // B*NBLK*2     =  16384 floats
  float* partial  = blkstats + (size_t)BB * NBLK * 2;     // NSPLIT*B*D   = 131072 floats

  k_score   <<<dim3(SS / 16, BB), 256, 0, stream>>>(src, tgt, score, blkstats);
  k_weighted<<<dim3(NSPLIT, BB),  256, 0, stream>>>(src, score, blkstats, pos, partial);
  k_out     <<<dim3(OO / OTILE, 1), 256, 0, stream>>>(tgt, partial, W, out);
}

// Round 4
// 688.588 us; speedup vs baseline: 1.0498x; 1.0498x over previous
//
#include <hip/hip_runtime.h>

#define BB 32
#define SS 4096
#define DD 1024
#define OO 1024
#define KK 2048
#define RAD 64
#define NSPLIT 8
#define NBLK (SS / 16)  // k_score blocks per batch = 256

typedef float f4 __attribute__((ext_vector_type(4)));

__device__ __forceinline__ float dot4(f4 a, f4 q) {
  return a.x * q.x + a.y * q.y + a.z * q.z + a.w * q.w;
}

// ---- Kernel 1: score[b,s] = dot(src[b,s,:], tgt[b,:]) + fused block softmax partials ----
// (identical to the 687 us Round-2 version)
__global__ __launch_bounds__(256) void k_score(const float* __restrict__ src,
                                               const float* __restrict__ tgt,
                                               float* __restrict__ score,
                                               float* __restrict__ blkstats) {
  const int b = blockIdx.y;
  const int wave = threadIdx.x >> 6;
  const int lane = threadIdx.x & 63;
  const int s_base = blockIdx.x * 16 + wave * 4;

  const f4* tv = (const f4*)(tgt + (size_t)b * DD);
  f4 q0 = tv[lane], q1 = tv[64 + lane], q2 = tv[128 + lane], q3 = tv[192 + lane];

  const f4* r0 = (const f4*)(src + ((size_t)b * SS + s_base) * DD) + lane;
  const f4* r1 = r0 + 256;
  const f4* r2 = r0 + 512;
  const f4* r3 = r0 + 768;

  f4 a00 = __builtin_nontemporal_load(r0);
  f4 a01 = __builtin_nontemporal_load(r0 + 64);
  f4 a02 = __builtin_nontemporal_load(r0 + 128);
  f4 a03 = __builtin_nontemporal_load(r0 + 192);
  f4 a10 = __builtin_nontemporal_load(r1);
  f4 a11 = __builtin_nontemporal_load(r1 + 64);
  f4 a12 = __builtin_nontemporal_load(r1 + 128);
  f4 a13 = __builtin_nontemporal_load(r1 + 192);
  f4 a20 = __builtin_nontemporal_load(r2);
  f4 a21 = __builtin_nontemporal_load(r2 + 64);
  f4 a22 = __builtin_nontemporal_load(r2 + 128);
  f4 a23 = __builtin_nontemporal_load(r2 + 192);
  f4 a30 = __builtin_nontemporal_load(r3);
  f4 a31 = __builtin_nontemporal_load(r3 + 64);
  f4 a32 = __builtin_nontemporal_load(r3 + 128);
  f4 a33 = __builtin_nontemporal_load(r3 + 192);

  float p0 = (dot4(a00, q0) + dot4(a01, q1)) + (dot4(a02, q2) + dot4(a03, q3));
  float p1 = (dot4(a10, q0) + dot4(a11, q1)) + (dot4(a12, q2) + dot4(a13, q3));
  float p2 = (dot4(a20, q0) + dot4(a21, q1)) + (dot4(a22, q2) + dot4(a23, q3));
  float p3 = (dot4(a30, q0) + dot4(a31, q1)) + (dot4(a32, q2) + dot4(a33, q3));

  for (int off = 32; off > 0; off >>= 1) {
    p0 += __shfl_xor(p0, off);
    p1 += __shfl_xor(p1, off);
    p2 += __shfl_xor(p2, off);
    p3 += __shfl_xor(p3, off);
  }

  float sel = (lane == 0) ? p0 : ((lane == 1) ? p1 : ((lane == 2) ? p2 : p3));
  if (lane < 4) score[(size_t)b * SS + s_base + lane] = sel;

  __shared__ float rowv[16];
  if (lane < 4) rowv[wave * 4 + lane] = sel;
  __syncthreads();
  if (threadIdx.x == 0) {
    float m = rowv[0];
    #pragma unroll
    for (int i = 1; i < 16; ++i) m = fmaxf(m, rowv[i]);
    float l = 0.f;
    #pragma unroll
    for (int i = 0; i < 16; ++i) l += expf(rowv[i] - m);
    float* bs = blkstats + ((size_t)b * NBLK + blockIdx.x) * 2;
    bs[0] = m; bs[1] = l;
  }
}

// ---- Kernel 2: combine 256 per-block (m,l) partials per batch -> stats[b] ----
// (identical to the 687 us Round-2 version)
__global__ __launch_bounds__(256) void k_combine(const float* __restrict__ blkstats,
                                                 float* __restrict__ stats) {
  const int b = blockIdx.x;
  const int wave = threadIdx.x >> 6;
  const int lane = threadIdx.x & 63;
  const float* bs = blkstats + ((size_t)b * NBLK + threadIdx.x) * 2;
  float m = bs[0];
  float l = bs[1];
  for (int off = 32; off > 0; off >>= 1) {
    float m2 = __shfl_xor(m, off);
    float l2 = __shfl_xor(l, off);
    float mm = fmaxf(m, m2);
    l = l * expf(m - mm) + l2 * expf(m2 - mm);
    m = mm;
  }
  __shared__ float sm[4], sl[4];
  if (lane == 0) { sm[wave] = m; sl[wave] = l; }
  __syncthreads();
  if (threadIdx.x == 0) {
    float M = fmaxf(fmaxf(sm[0], sm[1]), fmaxf(sm[2], sm[3]));
    float L = sl[0] * expf(sm[0] - M) + sl[1] * expf(sm[1] - M) +
              sl[2] * expf(sm[2] - M) + sl[3] * expf(sm[3] - M);
    stats[2 * b] = M;
    stats[2 * b + 1] = L;
  }
}

// ---- Kernel 3: windowed weighted sum (changed this round) ----
// pos_w = exp(-rel^2/128) < 1e-14 beyond |rel|=64 -> window [pos-64, pos+64].
// Changes vs Round 2: single fused expf (exp(sc-M-rel^2/128)), 1-deep software
// pipeline on (score, src-row) loads, 1/L hoisted to a final scale.
__global__ __launch_bounds__(256) void k_weighted(const float* __restrict__ src,
                                                  const float* __restrict__ score,
                                                  const float* __restrict__ stats,
                                                  const int* __restrict__ pos,
                                                  float* __restrict__ partial) {
  const int b = blockIdx.y;
  const int split = blockIdx.x;
  const int p = pos[b];
  int w0 = p - RAD; if (w0 < 0) w0 = 0;
  int w1 = p + RAD + 1; if (w1 > SS) w1 = SS;
  const int len = w1 - w0;
  const int chunk = (len + NSPLIT - 1) / NSPLIT;
  int cs = w0 + split * chunk;
  int ce = cs + chunk; if (ce > w1) ce = w1;
  const float M = stats[2 * b];
  const float inv = 1.f / stats[2 * b + 1];
  const int t = threadIdx.x;
  const float* srow = src + (size_t)b * SS * DD;
  const float* srb = score + (size_t)b * SS;

  f4 acc = (f4)(0.f);
  int s = cs;
  float sc = 0.f;
  f4 v = (f4)(0.f);
  if (s < ce) {
    sc = srb[s];
    v = ((const f4*)(srow + (size_t)s * DD))[t];
  }
  while (s < ce) {
    const int sn = s + 1;
    float scn = 0.f;
    f4 vn = (f4)(0.f);
    if (sn < ce) {
      scn = srb[sn];
      vn = ((const f4*)(srow + (size_t)sn * DD))[t];
    }
    const float rel = (float)(s - p);
    const float e = expf(sc - M - rel * rel * (1.f / 128.f));
    acc += e * v;
    s = sn; sc = scn; v = vn;
  }
  acc *= inv;
  f4* outp = (f4*)(partial + ((size_t)split * BB + b) * DD);
  outp[t] = acc;  // always write: ws is re-poisoned
}

// ---- Kernel 4: out[b,o] = tanh( [tgt, weighted] @ W ) ----
// (identical to the 687 us Round-2 version)
__global__ __launch_bounds__(256) void k_out(const float* __restrict__ tgt,
                                             const float* __restrict__ partial,
                                             const float* __restrict__ W,
                                             float* __restrict__ out) {
  const int b = blockIdx.y;
  const int o0 = blockIdx.x * 128;
  __shared__ float c[KK];
  __shared__ float red[4][128];
  for (int k = threadIdx.x; k < KK; k += 256) {
    float v;
    if (k < DD) {
      v = tgt[(size_t)b * DD + k];
    } else {
      const int d = k - DD;
      v = 0.f;
      for (int pp = 0; pp < NSPLIT; ++pp) v += partial[((size_t)pp * BB + b) * DD + d];
    }
    c[k] = v;
  }
  __syncthreads();
  const int ks = threadIdx.x >> 6;   // k-quarter
  const int ol = threadIdx.x & 63;   // o-pair lane
  float acc0 = 0.f, acc1 = 0.f;
  const float* wp = W + o0 + ol * 2;
  for (int k = ks * 512; k < ks * 512 + 512; ++k) {
    float2 wv = *(const float2*)(wp + (size_t)k * OO);
    float ck = c[k];
    acc0 += ck * wv.x; acc1 += ck * wv.y;
  }
  red[ks][ol * 2] = acc0;
  red[ks][ol * 2 + 1] = acc1;
  __syncthreads();
  if (threadIdx.x < 128) {
    float s = red[0][threadIdx.x] + red[1][threadIdx.x] + red[2][threadIdx.x] + red[3][threadIdx.x];
    out[(size_t)b * OO + o0 + threadIdx.x] = tanhf(s);
  }
}

extern "C" void kernel_launch(void* const* d_in, const int* in_sizes, int n_in,
                              void* d_out, int out_size, void* d_ws, size_t ws_size,
                              hipStream_t stream) {
  const float* src = (const float*)d_in[0];
  const float* tgt = (const float*)d_in[1];
  const int* pos   = (const int*)d_in[2];
  const float* W   = (const float*)d_in[3];
  float* out = (float*)d_out;

  float* ws       = (float*)d_ws;
  float* score    = ws;                         // B*S          = 131072 floats
  float* stats    = score + (size_t)BB * SS;    // 2*B          = 64 floats
  float* partial  = stats + 2 * BB;             // NSPLIT*B*D   = 262144 floats
  float* blkstats = partial + (size_t)NSPLIT * BB * DD;  // B*NBLK*2 = 16384 floats

  k_score   <<<dim3(SS / 16, BB), 256, 0, stream>>>(src, tgt, score, blkstats);
  k_combine <<<BB,                256, 0, stream>>>(blkstats, stats);
  k_weighted<<<dim3(NSPLIT, BB),  256, 0, stream>>>(src, score, stats, pos, partial);
  k_out     <<<dim3(OO / 128, BB), 256, 0, stream>>>(tgt, partial, W, out);
}